// Round 1
// baseline (435.203 us; speedup 1.0000x reference)
//
#include <hip/hip_runtime.h>

#define NMESH 128
#define NMESH2 (128 * 128)
#define NMESH3 (128 * 128 * 128)
#define NPOINTS 100000
#define NCH 16

// One thread per (point, channel). Block = 256 threads = 16 points x 16 channels.
// tid = p*16 + c globally, so out[tid] is a fully coalesced store.
__global__ __launch_bounds__(256) void mesh_interp_kernel(
    const float* __restrict__ mesh,   // [16][128][128][128]
    const float* __restrict__ pts,    // [100000][3]
    float* __restrict__ out)          // [100000][16]
{
    const int tid = blockIdx.x * 256 + threadIdx.x;
    const int c = tid & (NCH - 1);
    const int p = tid >> 4;
    if (p >= NPOINTS) return;

    const float SP = 0.1f;  // (float)(12.8/128)
    const float px = pts[p * 3 + 0];
    const float py = pts[p * 3 + 1];
    const float pz = pts[p * 3 + 2];

    const float pcx = px / SP;
    const float pcy = py / SP;
    const float pcz = pz / SP;

    // round-half-even to match jnp.round / np.round
    const int rx = (int)rintf(pcx);
    const int ry = (int)rintf(pcy);
    const int rz = (int)rintf(pcz);

    const float dx = pcx - (float)rx;
    const float dy = pcy - (float)ry;
    const float dz = pcz - (float)rz;

    // TSC weights per dimension
    float wX[3], wY[3], wZ[3];
    wX[0] = (2.0f * dx - 1.0f) * (2.0f * dx - 1.0f) * 0.125f;
    wX[1] = 0.75f - dx * dx;
    wX[2] = (2.0f * dx + 1.0f) * (2.0f * dx + 1.0f) * 0.125f;
    wY[0] = (2.0f * dy - 1.0f) * (2.0f * dy - 1.0f) * 0.125f;
    wY[1] = 0.75f - dy * dy;
    wY[2] = (2.0f * dy + 1.0f) * (2.0f * dy + 1.0f) * 0.125f;
    wZ[0] = (2.0f * dz - 1.0f) * (2.0f * dz - 1.0f) * 0.125f;
    wZ[1] = 0.75f - dz * dz;
    wZ[2] = (2.0f * dz + 1.0f) * (2.0f * dz + 1.0f) * 0.125f;

    // periodic wrap via & 127 (handles -1 -> 127 and 128 -> 0)
    int xb[3], yb[3], zi[3];
#pragma unroll
    for (int k = 0; k < 3; ++k) {
        xb[k] = ((rx - 1 + k) & (NMESH - 1)) * NMESH2;
        yb[k] = ((ry - 1 + k) & (NMESH - 1)) * NMESH;
        zi[k] = ((rz - 1 + k) & (NMESH - 1));
    }

    const float* __restrict__ mc = mesh + (size_t)c * NMESH3;
    float acc = 0.0f;
#pragma unroll
    for (int a = 0; a < 3; ++a) {
#pragma unroll
        for (int b = 0; b < 3; ++b) {
            const float* __restrict__ row = mc + xb[a] + yb[b];
            const float wxy = wX[a] * wY[b];
            acc = fmaf(row[zi[0]], wxy * wZ[0], acc);
            acc = fmaf(row[zi[1]], wxy * wZ[1], acc);
            acc = fmaf(row[zi[2]], wxy * wZ[2], acc);
        }
    }

    out[tid] = acc;  // tid == p*16 + c
}

extern "C" void kernel_launch(void* const* d_in, const int* in_sizes, int n_in,
                              void* d_out, int out_size, void* d_ws, size_t ws_size,
                              hipStream_t stream) {
    const float* mesh = (const float*)d_in[0];  // 16*128^3 floats
    const float* pts  = (const float*)d_in[1];  // 100000*3 floats
    float* out        = (float*)d_out;          // 100000*16 floats

    const int total = NPOINTS * NCH;            // 1,600,000
    const int block = 256;
    const int grid  = (total + block - 1) / block;  // 6250
    mesh_interp_kernel<<<grid, block, 0, stream>>>(mesh, pts, out);
}

// Round 2
// 226.148 us; speedup vs baseline: 1.9244x; 1.9244x over previous
//
#include <hip/hip_runtime.h>
#include <hip/hip_fp16.h>

#define NMESH 128
#define NMESH2 (128 * 128)
#define NMESH3 (128 * 128 * 128)
#define NPOINTS 100000
#define NCH 16

// ---------------------------------------------------------------------------
// Kernel 1: transpose (C,X,Y,Z) fp32 -> (X,Y,Z,C) fp16 in workspace.
// Pure permute of (c, s) -> (s, c) where s = spatial linear index (x*128+y)*128+z.
// Block = 256 threads handles a tile of 64 spatial x 16 channels.
// ---------------------------------------------------------------------------
__global__ __launch_bounds__(256) void transpose_to_half_kernel(
    const float* __restrict__ in,   // [16][2M]
    __half* __restrict__ outT)      // [2M][16]
{
    __shared__ float tile[64 * 17];  // row stride 17 breaks bank conflicts
    const int t = threadIdx.x;
    const int s_base = blockIdx.x * 64;
    const int lane = t & 63;
    const int c0 = t >> 6;  // 0..3

    // Read: per k, 4 segments of 64 consecutive floats (256 B each), one per c.
#pragma unroll
    for (int k = 0; k < 4; ++k) {
        const int c = c0 * 4 + k;
        tile[lane * 17 + c] = in[(size_t)c * NMESH3 + s_base + lane];
    }
    __syncthreads();

    // Write: 1024 halves = 512 packed uints, fully coalesced.
    uint32_t* out32 = (uint32_t*)(outT + (size_t)s_base * NCH);
#pragma unroll
    for (int k = 0; k < 2; ++k) {
        const int idx = t + 256 * k;   // 0..511 (pair index)
        const int s = idx >> 3;        // 0..63
        const int cp = idx & 7;        // 0..7 (channel pair)
        const float v0 = tile[s * 17 + cp * 2];
        const float v1 = tile[s * 17 + cp * 2 + 1];
        const uint32_t packed =
            (uint32_t)__half_as_ushort(__float2half(v0)) |
            ((uint32_t)__half_as_ushort(__float2half(v1)) << 16);
        out32[s * 8 + cp] = packed;
    }
}

// ---------------------------------------------------------------------------
// Kernel 2: gather from transposed fp16 mesh. 16 lanes per point (lane = ch);
// each of the 27 taps is one contiguous 32 B segment (16 ch x 2 B).
// ---------------------------------------------------------------------------
__global__ __launch_bounds__(256) void gather_half_kernel(
    const __half* __restrict__ meshT,  // [2M][16]
    const float* __restrict__ pts,     // [100000][3]
    float* __restrict__ out)           // [100000][16]
{
    const int tid = blockIdx.x * 256 + threadIdx.x;
    const int c = tid & (NCH - 1);
    const int p = tid >> 4;
    if (p >= NPOINTS) return;

    const float SP = 0.1f;
    const float pcx = pts[p * 3 + 0] / SP;
    const float pcy = pts[p * 3 + 1] / SP;
    const float pcz = pts[p * 3 + 2] / SP;

    const int rx = (int)rintf(pcx);
    const int ry = (int)rintf(pcy);
    const int rz = (int)rintf(pcz);

    const float dx = pcx - (float)rx;
    const float dy = pcy - (float)ry;
    const float dz = pcz - (float)rz;

    float wX[3], wY[3], wZ[3];
    wX[0] = (2.0f * dx - 1.0f) * (2.0f * dx - 1.0f) * 0.125f;
    wX[1] = 0.75f - dx * dx;
    wX[2] = (2.0f * dx + 1.0f) * (2.0f * dx + 1.0f) * 0.125f;
    wY[0] = (2.0f * dy - 1.0f) * (2.0f * dy - 1.0f) * 0.125f;
    wY[1] = 0.75f - dy * dy;
    wY[2] = (2.0f * dy + 1.0f) * (2.0f * dy + 1.0f) * 0.125f;
    wZ[0] = (2.0f * dz - 1.0f) * (2.0f * dz - 1.0f) * 0.125f;
    wZ[1] = 0.75f - dz * dz;
    wZ[2] = (2.0f * dz + 1.0f) * (2.0f * dz + 1.0f) * 0.125f;

    int xo[3], yo[3], zo[3];
#pragma unroll
    for (int k = 0; k < 3; ++k) {
        xo[k] = ((rx - 1 + k) & (NMESH - 1)) * (NMESH2 * NCH);
        yo[k] = ((ry - 1 + k) & (NMESH - 1)) * (NMESH * NCH);
        zo[k] = ((rz - 1 + k) & (NMESH - 1)) * NCH + c;
    }

    float acc = 0.0f;
#pragma unroll
    for (int a = 0; a < 3; ++a) {
#pragma unroll
        for (int b = 0; b < 3; ++b) {
            const int base = xo[a] + yo[b];
            const float wxy = wX[a] * wY[b];
            acc = fmaf(__half2float(meshT[base + zo[0]]), wxy * wZ[0], acc);
            acc = fmaf(__half2float(meshT[base + zo[1]]), wxy * wZ[1], acc);
            acc = fmaf(__half2float(meshT[base + zo[2]]), wxy * wZ[2], acc);
        }
    }

    out[tid] = acc;
}

// ---------------------------------------------------------------------------
// Fallback (round-1 kernel) in case ws_size is too small for the fp16 mesh.
// ---------------------------------------------------------------------------
__global__ __launch_bounds__(256) void mesh_interp_fallback_kernel(
    const float* __restrict__ mesh,
    const float* __restrict__ pts,
    float* __restrict__ out)
{
    const int tid = blockIdx.x * 256 + threadIdx.x;
    const int c = tid & (NCH - 1);
    const int p = tid >> 4;
    if (p >= NPOINTS) return;

    const float SP = 0.1f;
    const float pcx = pts[p * 3 + 0] / SP;
    const float pcy = pts[p * 3 + 1] / SP;
    const float pcz = pts[p * 3 + 2] / SP;

    const int rx = (int)rintf(pcx);
    const int ry = (int)rintf(pcy);
    const int rz = (int)rintf(pcz);

    const float dx = pcx - (float)rx;
    const float dy = pcy - (float)ry;
    const float dz = pcz - (float)rz;

    float wX[3], wY[3], wZ[3];
    wX[0] = (2.0f * dx - 1.0f) * (2.0f * dx - 1.0f) * 0.125f;
    wX[1] = 0.75f - dx * dx;
    wX[2] = (2.0f * dx + 1.0f) * (2.0f * dx + 1.0f) * 0.125f;
    wY[0] = (2.0f * dy - 1.0f) * (2.0f * dy - 1.0f) * 0.125f;
    wY[1] = 0.75f - dy * dy;
    wY[2] = (2.0f * dy + 1.0f) * (2.0f * dy + 1.0f) * 0.125f;
    wZ[0] = (2.0f * dz - 1.0f) * (2.0f * dz - 1.0f) * 0.125f;
    wZ[1] = 0.75f - dz * dz;
    wZ[2] = (2.0f * dz + 1.0f) * (2.0f * dz + 1.0f) * 0.125f;

    int xb[3], yb[3], zi[3];
#pragma unroll
    for (int k = 0; k < 3; ++k) {
        xb[k] = ((rx - 1 + k) & (NMESH - 1)) * NMESH2;
        yb[k] = ((ry - 1 + k) & (NMESH - 1)) * NMESH;
        zi[k] = ((rz - 1 + k) & (NMESH - 1));
    }

    const float* __restrict__ mc = mesh + (size_t)c * NMESH3;
    float acc = 0.0f;
#pragma unroll
    for (int a = 0; a < 3; ++a) {
#pragma unroll
        for (int b = 0; b < 3; ++b) {
            const float* __restrict__ row = mc + xb[a] + yb[b];
            const float wxy = wX[a] * wY[b];
            acc = fmaf(row[zi[0]], wxy * wZ[0], acc);
            acc = fmaf(row[zi[1]], wxy * wZ[1], acc);
            acc = fmaf(row[zi[2]], wxy * wZ[2], acc);
        }
    }
    out[tid] = acc;
}

extern "C" void kernel_launch(void* const* d_in, const int* in_sizes, int n_in,
                              void* d_out, int out_size, void* d_ws, size_t ws_size,
                              hipStream_t stream) {
    const float* mesh = (const float*)d_in[0];
    const float* pts  = (const float*)d_in[1];
    float* out        = (float*)d_out;

    const size_t needed = (size_t)NMESH3 * NCH * sizeof(__half);  // 64 MiB

    if (ws_size >= needed) {
        __half* meshT = (__half*)d_ws;
        transpose_to_half_kernel<<<NMESH3 / 64, 256, 0, stream>>>(mesh, meshT);
        const int total = NPOINTS * NCH;
        gather_half_kernel<<<(total + 255) / 256, 256, 0, stream>>>(meshT, pts, out);
    } else {
        const int total = NPOINTS * NCH;
        mesh_interp_fallback_kernel<<<(total + 255) / 256, 256, 0, stream>>>(mesh, pts, out);
    }
}